// Round 14
// baseline (86.950 us; speedup 1.0000x reference)
//
#include <hip/hip_runtime.h>

// FlowNetC fused: f1=conv3x3(x1,w), f2=conv3x3(x2,w),
// out[b,k,h,w] = mean_c f1[b,c,h,w]*f2[b,c,h+dy,w+dx], dy,dx in {-2,0,2}
// B=16,C=3,H=W=512,K=9. f32.
//
// R14 = R10 (best, 58.3us) + counted-vmcnt split first barrier:
//  - stage x1 FIRST, then x2 (x1 ops are older in the vmcnt queue)
//  - interior blocks: s_waitcnt vmcnt(4) + s_barrier  -> all x1 landed,
//    x2 (<=5 younger loads/thread) may still fly; f1 computes under it
//  - edge blocks (scalar staging fallbacks make counts unknowable):
//    full __syncthreads
//  - then full __syncthreads (vmcnt 0) before f2 reads s_x2
// Phase order: stage -> bar1 -> f1 -> bar2 -> f2+write -> bar3 -> corr.
// Everything else identical to R10: overlay s_ov (x1 then f2), conflict-
// free f2 mapping, scalar-pipe weights, width-16 global_load_lds, NT
// dwordx4 stores, XCD swizzle. LDS 35.5KB -> 4 blocks/CU.

#define HH 512
#define WW 512
#define TS 32
#define X2R 38
#define X2S 40              // x2 stride, rows 160B-aligned
#define X1R 34
#define X1S 36              // x1 stride, rows 144B-aligned
#define F2R 36
#define F2S 40
#define N2 (3*X2R*X2S)      // 4560 words
#define NF (3*F2R*F2S)      // 4320 words (overlay region size)
#define NC2 (3*X2R*(X2S/4)) // 1140 16B chunks
#define NC1 (3*X1R*(X1S/4)) // 918

typedef const __attribute__((address_space(1))) void* gas_ptr;
typedef __attribute__((address_space(3))) void* las_ptr;
typedef float f32x4 __attribute__((ext_vector_type(4)));

__global__ __launch_bounds__(256)
void flownetc_fused_kernel(const float* __restrict__ x1,
                           const float* __restrict__ x2,
                           const float* __restrict__ cw,
                           float* __restrict__ out) {
  __shared__ __align__(16) float s_x2[N2];
  __shared__ __align__(16) float s_ov[NF];   // x1 staging (first NC1*4) then f2

  const int tid = threadIdx.x;
  // XCD-contiguous swizzle: 4096 blocks / 8 XCDs = 512 contiguous each
  const int bid = blockIdx.x;
  const int f   = (bid & 7) * 512 + (bid >> 3);
  const int ox0 = (f & 15) * TS;
  const int oy0 = ((f >> 4) & 15) * TS;
  const int bi  = f >> 8;

  const float* x2b = x2 + (size_t)bi * 3 * HH * WW;
  const float* x1b = x1 + (size_t)bi * 3 * HH * WW;

  // interior: every staged chunk (x1 and x2) is fully in-bounds -> pure
  // async path, per-thread outstanding counts are exact
  const bool interior = (ox0 >= 32) && (ox0 <= 448) && (oy0 >= 32) && (oy0 <= 448);

  // ---- stage x1 [3][34][36] origin (oy0-1, ox0-1) into s_ov (FIRST) ----
  for (int q = tid; q < NC1; q += 256) {
    const int colq = q % (X1S / 4);
    const int rp   = q / (X1S / 4);
    const int r    = rp % X1R;
    const int c    = rp / X1R;
    const int gy   = oy0 - 1 + r;
    const int gx0  = ox0 - 1 + colq * 4;
    const float* src = x1b + (size_t)(c * HH + gy) * WW + gx0;
    if ((unsigned)gy < HH && (unsigned)gx0 <= (WW - 4)) {
      __builtin_amdgcn_global_load_lds((gas_ptr)src,
          (las_ptr)(s_ov + ((q & ~63) << 2)), 16, 0, 0);
    } else {
      const bool rowok = (unsigned)gy < HH;
      float4 v;
      v.x = (rowok && (unsigned)(gx0 + 0) < WW) ? src[0] : 0.f;
      v.y = (rowok && (unsigned)(gx0 + 1) < WW) ? src[1] : 0.f;
      v.z = (rowok && (unsigned)(gx0 + 2) < WW) ? src[2] : 0.f;
      v.w = (rowok && (unsigned)(gx0 + 3) < WW) ? src[3] : 0.f;
      *reinterpret_cast<float4*>(&s_ov[q * 4]) = v;
    }
  }
  // ---- stage x2 [3][38][40] origin (oy0-3, ox0-3) (SECOND, younger) ----
  for (int q = tid; q < NC2; q += 256) {
    const int colq = q % (X2S / 4);
    const int rp   = q / (X2S / 4);
    const int r    = rp % X2R;
    const int c    = rp / X2R;
    const int gy   = oy0 - 3 + r;
    const int gx0  = ox0 - 3 + colq * 4;
    const float* src = x2b + (size_t)(c * HH + gy) * WW + gx0;
    if ((unsigned)gy < HH && (unsigned)gx0 <= (WW - 4)) {
      __builtin_amdgcn_global_load_lds((gas_ptr)src,
          (las_ptr)(s_x2 + ((q & ~63) << 2)), 16, 0, 0);
    } else {
      const bool rowok = (unsigned)gy < HH;
      float4 v;
      v.x = (rowok && (unsigned)(gx0 + 0) < WW) ? src[0] : 0.f;
      v.y = (rowok && (unsigned)(gx0 + 1) < WW) ? src[1] : 0.f;
      v.z = (rowok && (unsigned)(gx0 + 2) < WW) ? src[2] : 0.f;
      v.w = (rowok && (unsigned)(gx0 + 3) < WW) ? src[3] : 0.f;
      *reinterpret_cast<float4*>(&s_x2[q * 4]) = v;
    }
  }

  // ---- bar1: x1 guaranteed landed; x2 may still fly (interior) ----
  if (interior) {
    asm volatile("s_waitcnt vmcnt(4)" ::: "memory");
    __builtin_amdgcn_s_barrier();
    __builtin_amdgcn_sched_barrier(0);
  } else {
    __syncthreads();
  }

  // ---- f1 (regs) from s_ov-as-x1, hides x2 staging tail ----
  const int py  = tid >> 3;
  const int px0 = (tid & 7) << 2;
  float f1r[3][4] = {};
  #pragma unroll
  for (int ci = 0; ci < 3; ++ci) {
    float win[3][6];
    #pragma unroll
    for (int ky = 0; ky < 3; ++ky) {
      const float* base = &s_ov[(ci * X1R + py + ky) * X1S + px0];
      const float4 a  = *reinterpret_cast<const float4*>(base);
      const float2 b2 = *reinterpret_cast<const float2*>(base + 4);
      win[ky][0] = a.x; win[ky][1] = a.y; win[ky][2] = a.z; win[ky][3] = a.w;
      win[ky][4] = b2.x; win[ky][5] = b2.y;
    }
    #pragma unroll
    for (int co = 0; co < 3; ++co)
      #pragma unroll
      for (int ky = 0; ky < 3; ++ky)
        #pragma unroll
        for (int kx = 0; kx < 3; ++kx) {
          const float w = cw[((co * 3 + ci) * 3 + ky) * 3 + kx]; // SGPR
          #pragma unroll
          for (int j = 0; j < 4; ++j)
            f1r[co][j] += w * win[ky][j + kx];
        }
  }
  #pragma unroll
  for (int co = 0; co < 3; ++co)
    #pragma unroll
    for (int j = 0; j < 4; ++j)
      f1r[co][j] *= (1.f / 3.f);     // fold mean divisor

  __syncthreads();   // bar2: drains vmcnt(0) -> all x2 landed; f1 reads done

  // ---- f2 (regs) from s_x2 ----
  auto f2unit = [&](int r, int col0, float acc[3][4]) {
    #pragma unroll
    for (int co = 0; co < 3; ++co)
      #pragma unroll
      for (int j = 0; j < 4; ++j) acc[co][j] = 0.f;
    #pragma unroll
    for (int ci = 0; ci < 3; ++ci) {
      float win[3][6];
      #pragma unroll
      for (int ky = 0; ky < 3; ++ky) {
        const float* base = &s_x2[(ci * X2R + r + ky) * X2S + col0];
        const float4 a  = *reinterpret_cast<const float4*>(base);
        const float2 b2 = *reinterpret_cast<const float2*>(base + 4);
        win[ky][0] = a.x; win[ky][1] = a.y; win[ky][2] = a.z; win[ky][3] = a.w;
        win[ky][4] = b2.x; win[ky][5] = b2.y;
      }
      #pragma unroll
      for (int co = 0; co < 3; ++co)
        #pragma unroll
        for (int ky = 0; ky < 3; ++ky)
          #pragma unroll
          for (int kx = 0; kx < 3; ++kx) {
            const float w = cw[((co * 3 + ci) * 3 + ky) * 3 + kx];
            #pragma unroll
            for (int j = 0; j < 4; ++j)
              acc[co][j] += w * win[ky][j + kx];
          }
    }
    // correlation zero-pads f2: zero outside the image
    const int gy = oy0 - 2 + r;
    #pragma unroll
    for (int j = 0; j < 4; ++j) {
      const int gx = ox0 - 2 + col0 + j;
      if (!((unsigned)gy < HH && (unsigned)gx < WW)) {
        acc[0][j] = 0.f; acc[1][j] = 0.f; acc[2][j] = 0.f;
      }
    }
  };

  const int r0 = tid >> 3;           // 0..31
  const int c0 = (tid & 7) << 2;     // 0..28
  float acc0[3][4];
  f2unit(r0, c0, acc0);
  float acc1[3][4];
  int r1 = 0, c1 = 0;
  if (tid < 68) {
    if (tid < 36) { r1 = 32 + tid / 9; c1 = (tid % 9) * 4; }
    else          { r1 = tid - 36;     c1 = 32; }
    f2unit(r1, c1, acc1);
  }

  // ---- write f2 regs into s_ov overlay (f1 reads finished at bar2) ----
  #pragma unroll
  for (int co = 0; co < 3; ++co)
    *reinterpret_cast<float4*>(&s_ov[(co * F2R + r0) * F2S + c0]) =
        make_float4(acc0[co][0], acc0[co][1], acc0[co][2], acc0[co][3]);
  if (tid < 68) {
    #pragma unroll
    for (int co = 0; co < 3; ++co)
      *reinterpret_cast<float4*>(&s_ov[(co * F2R + r1) * F2S + c1]) =
          make_float4(acc1[co][0], acc1[co][1], acc1[co][2], acc1[co][3]);
  }
  __syncthreads();   // bar3: f2 tile ready

  // ---- correlation + nontemporal dwordx4 stores ----
  float* outp = out + ((size_t)bi * 9 * HH + (oy0 + py)) * WW + ox0 + px0;
  #pragma unroll
  for (int dyi = 0; dyi < 3; ++dyi) {
    float rv[3][8];
    #pragma unroll
    for (int c = 0; c < 3; ++c) {
      const float* base = &s_ov[(c * F2R + py + dyi * 2) * F2S + px0];
      const float4 a = *reinterpret_cast<const float4*>(base);
      const float4 b = *reinterpret_cast<const float4*>(base + 4);
      rv[c][0] = a.x; rv[c][1] = a.y; rv[c][2] = a.z; rv[c][3] = a.w;
      rv[c][4] = b.x; rv[c][5] = b.y; rv[c][6] = b.z; rv[c][7] = b.w;
    }
    #pragma unroll
    for (int dxi = 0; dxi < 3; ++dxi) {
      const int s = dxi * 2;
      f32x4 o;
      o.x = f1r[0][0]*rv[0][s+0] + f1r[1][0]*rv[1][s+0] + f1r[2][0]*rv[2][s+0];
      o.y = f1r[0][1]*rv[0][s+1] + f1r[1][1]*rv[1][s+1] + f1r[2][1]*rv[2][s+1];
      o.z = f1r[0][2]*rv[0][s+2] + f1r[1][2]*rv[1][s+2] + f1r[2][2]*rv[2][s+2];
      o.w = f1r[0][3]*rv[0][s+3] + f1r[1][3]*rv[1][s+3] + f1r[2][3]*rv[2][s+3];
      __builtin_nontemporal_store(o,
          reinterpret_cast<f32x4*>(outp + (size_t)(dyi * 3 + dxi) * HH * WW));
    }
  }
}

extern "C" void kernel_launch(void* const* d_in, const int* in_sizes, int n_in,
                              void* d_out, int out_size, void* d_ws, size_t ws_size,
                              hipStream_t stream) {
  const float* x1 = (const float*)d_in[0];
  const float* x2 = (const float*)d_in[1];
  const float* cw = (const float*)d_in[2];
  float* out = (float*)d_out;

  flownetc_fused_kernel<<<dim3(4096), 256, 0, stream>>>(x1, x2, cw, out);
}

// Round 15
// 69.775 us; speedup vs baseline: 1.2462x; 1.2462x over previous
//
#include <hip/hip_runtime.h>

// FlowNetC fused: f1=conv3x3(x1,w), f2=conv3x3(x2,w),
// out[b,k,h,w] = mean_c f1[b,c,h,w]*f2[b,c,h+dy,w+dx], dy,dx in {-2,0,2}
// B=16,C=3,H=W=512,K=9. f32.
//
// R15: two-kernel split (guarded by ws_size; fallback = R10 fused kernel).
//  K1 conv2: x2 -> f2ws (planar [b][c][y][x], 50.3MB, 1/3 folded in).
//     32x32 tile, 34x34 stage (stride 36), plain float4 stores (L2/L3-
//     resident for K2).
//  K2 corr: stage x1 (34x34), f1 in regs, correlation reads f2ws from
//     GLOBAL (3 aligned float4 per window row; 9x L1/L2 reuse), NT stores.
//     One barrier, 13.9KB LDS.

#define HH 512
#define WW 512
#define TS 32
#define XR 34
#define XS 36
#define NCX (3*XR*(XS/4))   // 918 chunks
// R10 fallback geometry
#define X2R 38
#define X2S 40
#define X1R 34
#define X1S 36
#define F2R 36
#define F2S 40
#define N2 (3*X2R*X2S)
#define NF (3*F2R*F2S)
#define NC2 (3*X2R*(X2S/4))
#define NC1 (3*X1R*(X1S/4))

typedef const __attribute__((address_space(1))) void* gas_ptr;
typedef __attribute__((address_space(3))) void* las_ptr;
typedef float f32x4 __attribute__((ext_vector_type(4)));

// ---------------- K1: f2 conv ----------------
__global__ __launch_bounds__(256)
void conv2_kernel(const float* __restrict__ x2,
                  const float* __restrict__ cw,
                  float* __restrict__ f2ws) {
  __shared__ __align__(16) float s_x[3*XR*XS];   // 3672 w = 14.7KB
  const int tid = threadIdx.x;
  const int bid = blockIdx.x;
  const int f   = (bid & 7) * 512 + (bid >> 3);
  const int ox0 = (f & 15) * TS;
  const int oy0 = ((f >> 4) & 15) * TS;
  const int bi  = f >> 8;
  const float* x2b = x2 + (size_t)bi * 3 * HH * WW;

  for (int q = tid; q < NCX; q += 256) {
    const int colq = q % (XS / 4);
    const int rp   = q / (XS / 4);
    const int r    = rp % XR;
    const int c    = rp / XR;
    const int gy   = oy0 - 1 + r;
    const int gx0  = ox0 - 1 + colq * 4;
    const float* src = x2b + (size_t)(c * HH + gy) * WW + gx0;
    if ((unsigned)gy < HH && (unsigned)gx0 <= (WW - 4)) {
      __builtin_amdgcn_global_load_lds((gas_ptr)src,
          (las_ptr)(s_x + ((q & ~63) << 2)), 16, 0, 0);
    } else {
      const bool rowok = (unsigned)gy < HH;
      float4 v;
      v.x = (rowok && (unsigned)(gx0 + 0) < WW) ? src[0] : 0.f;
      v.y = (rowok && (unsigned)(gx0 + 1) < WW) ? src[1] : 0.f;
      v.z = (rowok && (unsigned)(gx0 + 2) < WW) ? src[2] : 0.f;
      v.w = (rowok && (unsigned)(gx0 + 3) < WW) ? src[3] : 0.f;
      *reinterpret_cast<float4*>(&s_x[q * 4]) = v;
    }
  }
  __syncthreads();

  const int py  = tid >> 3;
  const int px0 = (tid & 7) << 2;
  float fr[3][4] = {};
  #pragma unroll
  for (int ci = 0; ci < 3; ++ci) {
    float win[3][6];
    #pragma unroll
    for (int ky = 0; ky < 3; ++ky) {
      const float* base = &s_x[(ci * XR + py + ky) * XS + px0];
      const float4 a  = *reinterpret_cast<const float4*>(base);
      const float2 b2 = *reinterpret_cast<const float2*>(base + 4);
      win[ky][0] = a.x; win[ky][1] = a.y; win[ky][2] = a.z; win[ky][3] = a.w;
      win[ky][4] = b2.x; win[ky][5] = b2.y;
    }
    #pragma unroll
    for (int co = 0; co < 3; ++co)
      #pragma unroll
      for (int ky = 0; ky < 3; ++ky)
        #pragma unroll
        for (int kx = 0; kx < 3; ++kx) {
          const float w = cw[((co * 3 + ci) * 3 + ky) * 3 + kx]; // SGPR
          #pragma unroll
          for (int j = 0; j < 4; ++j)
            fr[co][j] += w * win[ky][j + kx];
        }
  }
  #pragma unroll
  for (int co = 0; co < 3; ++co) {
    #pragma unroll
    for (int j = 0; j < 4; ++j) fr[co][j] *= (1.f / 3.f);  // fold mean here
    *reinterpret_cast<float4*>(
        f2ws + ((size_t)(bi * 3 + co) * HH + oy0 + py) * WW + ox0 + px0) =
        make_float4(fr[co][0], fr[co][1], fr[co][2], fr[co][3]);
  }
}

// ---------------- K2: f1 + correlation ----------------
__global__ __launch_bounds__(256)
void corr_kernel(const float* __restrict__ x1,
                 const float* __restrict__ cw,
                 const float* __restrict__ f2ws,
                 float* __restrict__ out) {
  __shared__ __align__(16) float s_x[3*XR*XS];
  const int tid = threadIdx.x;
  const int bid = blockIdx.x;
  const int f   = (bid & 7) * 512 + (bid >> 3);
  const int ox0 = (f & 15) * TS;
  const int oy0 = ((f >> 4) & 15) * TS;
  const int bi  = f >> 8;
  const float* x1b = x1 + (size_t)bi * 3 * HH * WW;

  for (int q = tid; q < NCX; q += 256) {
    const int colq = q % (XS / 4);
    const int rp   = q / (XS / 4);
    const int r    = rp % XR;
    const int c    = rp / XR;
    const int gy   = oy0 - 1 + r;
    const int gx0  = ox0 - 1 + colq * 4;
    const float* src = x1b + (size_t)(c * HH + gy) * WW + gx0;
    if ((unsigned)gy < HH && (unsigned)gx0 <= (WW - 4)) {
      __builtin_amdgcn_global_load_lds((gas_ptr)src,
          (las_ptr)(s_x + ((q & ~63) << 2)), 16, 0, 0);
    } else {
      const bool rowok = (unsigned)gy < HH;
      float4 v;
      v.x = (rowok && (unsigned)(gx0 + 0) < WW) ? src[0] : 0.f;
      v.y = (rowok && (unsigned)(gx0 + 1) < WW) ? src[1] : 0.f;
      v.z = (rowok && (unsigned)(gx0 + 2) < WW) ? src[2] : 0.f;
      v.w = (rowok && (unsigned)(gx0 + 3) < WW) ? src[3] : 0.f;
      *reinterpret_cast<float4*>(&s_x[q * 4]) = v;
    }
  }
  __syncthreads();

  const int py  = tid >> 3;
  const int px0 = (tid & 7) << 2;
  float f1r[3][4] = {};
  #pragma unroll
  for (int ci = 0; ci < 3; ++ci) {
    float win[3][6];
    #pragma unroll
    for (int ky = 0; ky < 3; ++ky) {
      const float* base = &s_x[(ci * XR + py + ky) * XS + px0];
      const float4 a  = *reinterpret_cast<const float4*>(base);
      const float2 b2 = *reinterpret_cast<const float2*>(base + 4);
      win[ky][0] = a.x; win[ky][1] = a.y; win[ky][2] = a.z; win[ky][3] = a.w;
      win[ky][4] = b2.x; win[ky][5] = b2.y;
    }
    #pragma unroll
    for (int co = 0; co < 3; ++co)
      #pragma unroll
      for (int ky = 0; ky < 3; ++ky)
        #pragma unroll
        for (int kx = 0; kx < 3; ++kx) {
          const float w = cw[((co * 3 + ci) * 3 + ky) * 3 + kx];
          #pragma unroll
          for (int j = 0; j < 4; ++j)
            f1r[co][j] += w * win[ky][j + kx];
        }
  }

  // ---- correlation: f2 windows from global (L1/L2-cached) ----
  const int gy  = oy0 + py;
  const int gx0 = ox0 + px0;
  const bool xedge = (ox0 == 0) || (ox0 == (WW - TS));  // block-uniform
  float* outp = out + ((size_t)bi * 9 * HH + gy) * WW + gx0;
  #pragma unroll
  for (int dyi = 0; dyi < 3; ++dyi) {
    const int gyd  = gy + dyi * 2 - 2;
    const int gyc  = gyd < 0 ? 0 : (gyd >= HH ? HH - 1 : gyd);
    const float mrow = ((unsigned)gyd < HH) ? 1.f : 0.f;
    float rv[3][8];
    #pragma unroll
    for (int c = 0; c < 3; ++c) {
      const float* prow = f2ws + ((size_t)(bi * 3 + c) * HH + gyc) * WW;
      if (!xedge) {
        const float4 a = *reinterpret_cast<const float4*>(prow + gx0 - 4);
        const float4 b = *reinterpret_cast<const float4*>(prow + gx0);
        const float4 d = *reinterpret_cast<const float4*>(prow + gx0 + 4);
        rv[c][0] = mrow * a.z; rv[c][1] = mrow * a.w;
        rv[c][2] = mrow * b.x; rv[c][3] = mrow * b.y;
        rv[c][4] = mrow * b.z; rv[c][5] = mrow * b.w;
        rv[c][6] = mrow * d.x; rv[c][7] = mrow * d.y;
      } else {
        #pragma unroll
        for (int i = 0; i < 8; ++i) {
          const int xi = gx0 - 2 + i;
          const int xc = xi < 0 ? 0 : (xi >= WW ? WW - 1 : xi);
          const float mx = ((unsigned)xi < WW) ? mrow : 0.f;
          rv[c][i] = mx * prow[xc];
        }
      }
    }
    #pragma unroll
    for (int dxi = 0; dxi < 3; ++dxi) {
      const int s = dxi * 2;
      f32x4 o;
      o.x = f1r[0][0]*rv[0][s+0] + f1r[1][0]*rv[1][s+0] + f1r[2][0]*rv[2][s+0];
      o.y = f1r[0][1]*rv[0][s+1] + f1r[1][1]*rv[1][s+1] + f1r[2][1]*rv[2][s+1];
      o.z = f1r[0][2]*rv[0][s+2] + f1r[1][2]*rv[1][s+2] + f1r[2][2]*rv[2][s+2];
      o.w = f1r[0][3]*rv[0][s+3] + f1r[1][3]*rv[1][s+3] + f1r[2][3]*rv[2][s+3];
      __builtin_nontemporal_store(o,
          reinterpret_cast<f32x4*>(outp + (size_t)(dyi * 3 + dxi) * HH * WW));
    }
  }
}

// ---------------- fallback: R10 fused kernel (58.3us) ----------------
__global__ __launch_bounds__(256)
void flownetc_fused_kernel(const float* __restrict__ x1,
                           const float* __restrict__ x2,
                           const float* __restrict__ cw,
                           float* __restrict__ out) {
  __shared__ __align__(16) float s_x2[N2];
  __shared__ __align__(16) float s_ov[NF];
  const int tid = threadIdx.x;
  const int bid = blockIdx.x;
  const int f   = (bid & 7) * 512 + (bid >> 3);
  const int ox0 = (f & 15) * TS;
  const int oy0 = ((f >> 4) & 15) * TS;
  const int bi  = f >> 8;
  const float* x2b = x2 + (size_t)bi * 3 * HH * WW;
  const float* x1b = x1 + (size_t)bi * 3 * HH * WW;

  for (int q = tid; q < NC2; q += 256) {
    const int colq = q % (X2S / 4);
    const int rp   = q / (X2S / 4);
    const int r    = rp % X2R;
    const int c    = rp / X2R;
    const int gy   = oy0 - 3 + r;
    const int gx0  = ox0 - 3 + colq * 4;
    const float* src = x2b + (size_t)(c * HH + gy) * WW + gx0;
    if ((unsigned)gy < HH && (unsigned)gx0 <= (WW - 4)) {
      __builtin_amdgcn_global_load_lds((gas_ptr)src,
          (las_ptr)(s_x2 + ((q & ~63) << 2)), 16, 0, 0);
    } else {
      const bool rowok = (unsigned)gy < HH;
      float4 v;
      v.x = (rowok && (unsigned)(gx0 + 0) < WW) ? src[0] : 0.f;
      v.y = (rowok && (unsigned)(gx0 + 1) < WW) ? src[1] : 0.f;
      v.z = (rowok && (unsigned)(gx0 + 2) < WW) ? src[2] : 0.f;
      v.w = (rowok && (unsigned)(gx0 + 3) < WW) ? src[3] : 0.f;
      *reinterpret_cast<float4*>(&s_x2[q * 4]) = v;
    }
  }
  for (int q = tid; q < NC1; q += 256) {
    const int colq = q % (X1S / 4);
    const int rp   = q / (X1S / 4);
    const int r    = rp % X1R;
    const int c    = rp / X1R;
    const int gy   = oy0 - 1 + r;
    const int gx0  = ox0 - 1 + colq * 4;
    const float* src = x1b + (size_t)(c * HH + gy) * WW + gx0;
    if ((unsigned)gy < HH && (unsigned)gx0 <= (WW - 4)) {
      __builtin_amdgcn_global_load_lds((gas_ptr)src,
          (las_ptr)(s_ov + ((q & ~63) << 2)), 16, 0, 0);
    } else {
      const bool rowok = (unsigned)gy < HH;
      float4 v;
      v.x = (rowok && (unsigned)(gx0 + 0) < WW) ? src[0] : 0.f;
      v.y = (rowok && (unsigned)(gx0 + 1) < WW) ? src[1] : 0.f;
      v.z = (rowok && (unsigned)(gx0 + 2) < WW) ? src[2] : 0.f;
      v.w = (rowok && (unsigned)(gx0 + 3) < WW) ? src[3] : 0.f;
      *reinterpret_cast<float4*>(&s_ov[q * 4]) = v;
    }
  }
  __syncthreads();

  auto f2unit = [&](int r, int col0, float acc[3][4]) {
    #pragma unroll
    for (int co = 0; co < 3; ++co)
      #pragma unroll
      for (int j = 0; j < 4; ++j) acc[co][j] = 0.f;
    #pragma unroll
    for (int ci = 0; ci < 3; ++ci) {
      float win[3][6];
      #pragma unroll
      for (int ky = 0; ky < 3; ++ky) {
        const float* base = &s_x2[(ci * X2R + r + ky) * X2S + col0];
        const float4 a  = *reinterpret_cast<const float4*>(base);
        const float2 b2 = *reinterpret_cast<const float2*>(base + 4);
        win[ky][0] = a.x; win[ky][1] = a.y; win[ky][2] = a.z; win[ky][3] = a.w;
        win[ky][4] = b2.x; win[ky][5] = b2.y;
      }
      #pragma unroll
      for (int co = 0; co < 3; ++co)
        #pragma unroll
        for (int ky = 0; ky < 3; ++ky)
          #pragma unroll
          for (int kx = 0; kx < 3; ++kx) {
            const float w = cw[((co * 3 + ci) * 3 + ky) * 3 + kx];
            #pragma unroll
            for (int j = 0; j < 4; ++j)
              acc[co][j] += w * win[ky][j + kx];
          }
    }
    const int gy = oy0 - 2 + r;
    #pragma unroll
    for (int j = 0; j < 4; ++j) {
      const int gx = ox0 - 2 + col0 + j;
      if (!((unsigned)gy < HH && (unsigned)gx < WW)) {
        acc[0][j] = 0.f; acc[1][j] = 0.f; acc[2][j] = 0.f;
      }
    }
  };

  const int r0 = tid >> 3;
  const int c0 = (tid & 7) << 2;
  float acc0[3][4];
  f2unit(r0, c0, acc0);
  float acc1[3][4];
  int r1 = 0, c1 = 0;
  if (tid < 68) {
    if (tid < 36) { r1 = 32 + tid / 9; c1 = (tid % 9) * 4; }
    else          { r1 = tid - 36;     c1 = 32; }
    f2unit(r1, c1, acc1);
  }

  const int py  = tid >> 3;
  const int px0 = (tid & 7) << 2;
  float f1r[3][4] = {};
  #pragma unroll
  for (int ci = 0; ci < 3; ++ci) {
    float win[3][6];
    #pragma unroll
    for (int ky = 0; ky < 3; ++ky) {
      const float* base = &s_ov[(ci * X1R + py + ky) * X1S + px0];
      const float4 a  = *reinterpret_cast<const float4*>(base);
      const float2 b2 = *reinterpret_cast<const float2*>(base + 4);
      win[ky][0] = a.x; win[ky][1] = a.y; win[ky][2] = a.z; win[ky][3] = a.w;
      win[ky][4] = b2.x; win[ky][5] = b2.y;
    }
    #pragma unroll
    for (int co = 0; co < 3; ++co)
      #pragma unroll
      for (int ky = 0; ky < 3; ++ky)
        #pragma unroll
        for (int kx = 0; kx < 3; ++kx) {
          const float w = cw[((co * 3 + ci) * 3 + ky) * 3 + kx];
          #pragma unroll
          for (int j = 0; j < 4; ++j)
            f1r[co][j] += w * win[ky][j + kx];
        }
  }
  #pragma unroll
  for (int co = 0; co < 3; ++co)
    #pragma unroll
    for (int j = 0; j < 4; ++j)
      f1r[co][j] *= (1.f / 3.f);
  __syncthreads();

  #pragma unroll
  for (int co = 0; co < 3; ++co)
    *reinterpret_cast<float4*>(&s_ov[(co * F2R + r0) * F2S + c0]) =
        make_float4(acc0[co][0], acc0[co][1], acc0[co][2], acc0[co][3]);
  if (tid < 68) {
    #pragma unroll
    for (int co = 0; co < 3; ++co)
      *reinterpret_cast<float4*>(&s_ov[(co * F2R + r1) * F2S + c1]) =
          make_float4(acc1[co][0], acc1[co][1], acc1[co][2], acc1[co][3]);
  }
  __syncthreads();

  float* outp = out + ((size_t)bi * 9 * HH + (oy0 + py)) * WW + ox0 + px0;
  #pragma unroll
  for (int dyi = 0; dyi < 3; ++dyi) {
    float rv[3][8];
    #pragma unroll
    for (int c = 0; c < 3; ++c) {
      const float* base = &s_ov[(c * F2R + py + dyi * 2) * F2S + px0];
      const float4 a = *reinterpret_cast<const float4*>(base);
      const float4 b = *reinterpret_cast<const float4*>(base + 4);
      rv[c][0] = a.x; rv[c][1] = a.y; rv[c][2] = a.z; rv[c][3] = a.w;
      rv[c][4] = b.x; rv[c][5] = b.y; rv[c][6] = b.z; rv[c][7] = b.w;
    }
    #pragma unroll
    for (int dxi = 0; dxi < 3; ++dxi) {
      const int s = dxi * 2;
      f32x4 o;
      o.x = f1r[0][0]*rv[0][s+0] + f1r[1][0]*rv[1][s+0] + f1r[2][0]*rv[2][s+0];
      o.y = f1r[0][1]*rv[0][s+1] + f1r[1][1]*rv[1][s+1] + f1r[2][1]*rv[2][s+1];
      o.z = f1r[0][2]*rv[0][s+2] + f1r[1][2]*rv[1][s+2] + f1r[2][2]*rv[2][s+2];
      o.w = f1r[0][3]*rv[0][s+3] + f1r[1][3]*rv[1][s+3] + f1r[2][3]*rv[2][s+3];
      __builtin_nontemporal_store(o,
          reinterpret_cast<f32x4*>(outp + (size_t)(dyi * 3 + dxi) * HH * WW));
    }
  }
}

extern "C" void kernel_launch(void* const* d_in, const int* in_sizes, int n_in,
                              void* d_out, int out_size, void* d_ws, size_t ws_size,
                              hipStream_t stream) {
  const float* x1 = (const float*)d_in[0];
  const float* x2 = (const float*)d_in[1];
  const float* cw = (const float*)d_in[2];
  float* out = (float*)d_out;
  const size_t need = (size_t)16 * 3 * HH * WW * sizeof(float);  // 50.3 MB

  if (ws_size >= need && d_ws != nullptr) {
    float* f2ws = (float*)d_ws;
    conv2_kernel<<<dim3(4096), 256, 0, stream>>>(x2, cw, f2ws);
    corr_kernel<<<dim3(4096), 256, 0, stream>>>(x1, cw, f2ws, out);
  } else {
    flownetc_fused_kernel<<<dim3(4096), 256, 0, stream>>>(x1, x2, cw, out);
  }
}

// Round 16
// 58.060 us; speedup vs baseline: 1.4976x; 1.2018x over previous
//
#include <hip/hip_runtime.h>

// FlowNetC fused: f1=conv3x3(x1,w), f2=conv3x3(x2,w),
// out[b,k,h,w] = mean_c f1[b,c,h,w]*f2[b,c,h+dy,w+dx], dy,dx in {-2,0,2}
// B=16,C=3,H=W=512,K=9. f32.
//
// R16 = R10 verbatim (best known: 58.3us). Six structural perturbations
// (R6/R9/R11/R13/R14/R15) all regressed 10-30us; R10 is the local optimum:
// 32x32 tile / 256 thr, LDS overlay (x1 staging then f2 tile in s_ov),
// 3 barriers, conflict-free f2 mapping, scalar-pipe weights, width-16
// global_load_lds staging, 1/3 folded into f1, NT dwordx4 stores,
// XCD-contiguous swizzle. LDS 35.5KB -> 4 blocks/CU.

#define HH 512
#define WW 512
#define TS 32
#define X2R 38
#define X2S 40              // x2 stride, rows 160B-aligned
#define X1R 34
#define X1S 36              // x1 stride, rows 144B-aligned
#define F2R 36
#define F2S 40
#define N2 (3*X2R*X2S)      // 4560 words
#define NF (3*F2R*F2S)      // 4320 words (overlay region size)
#define NC2 (3*X2R*(X2S/4)) // 1140 16B chunks
#define NC1 (3*X1R*(X1S/4)) // 918

typedef const __attribute__((address_space(1))) void* gas_ptr;
typedef __attribute__((address_space(3))) void* las_ptr;
typedef float f32x4 __attribute__((ext_vector_type(4)));

__global__ __launch_bounds__(256)
void flownetc_fused_kernel(const float* __restrict__ x1,
                           const float* __restrict__ x2,
                           const float* __restrict__ cw,
                           float* __restrict__ out) {
  __shared__ __align__(16) float s_x2[N2];
  __shared__ __align__(16) float s_ov[NF];   // x1 staging (first NC1*4) then f2

  const int tid = threadIdx.x;
  // XCD-contiguous swizzle: 4096 blocks / 8 XCDs = 512 contiguous each
  const int bid = blockIdx.x;
  const int f   = (bid & 7) * 512 + (bid >> 3);
  const int ox0 = (f & 15) * TS;
  const int oy0 = ((f >> 4) & 15) * TS;
  const int bi  = f >> 8;

  const float* x2b = x2 + (size_t)bi * 3 * HH * WW;
  const float* x1b = x1 + (size_t)bi * 3 * HH * WW;

  // ---- stage x2 [3][38][40] origin (oy0-3, ox0-3), 16B chunks ----
  for (int q = tid; q < NC2; q += 256) {
    const int colq = q % (X2S / 4);
    const int rp   = q / (X2S / 4);
    const int r    = rp % X2R;
    const int c    = rp / X2R;
    const int gy   = oy0 - 3 + r;
    const int gx0  = ox0 - 3 + colq * 4;
    const float* src = x2b + (size_t)(c * HH + gy) * WW + gx0;
    if ((unsigned)gy < HH && (unsigned)gx0 <= (WW - 4)) {
      __builtin_amdgcn_global_load_lds((gas_ptr)src,
          (las_ptr)(s_x2 + ((q & ~63) << 2)), 16, 0, 0);
    } else {
      const bool rowok = (unsigned)gy < HH;
      float4 v;
      v.x = (rowok && (unsigned)(gx0 + 0) < WW) ? src[0] : 0.f;
      v.y = (rowok && (unsigned)(gx0 + 1) < WW) ? src[1] : 0.f;
      v.z = (rowok && (unsigned)(gx0 + 2) < WW) ? src[2] : 0.f;
      v.w = (rowok && (unsigned)(gx0 + 3) < WW) ? src[3] : 0.f;
      *reinterpret_cast<float4*>(&s_x2[q * 4]) = v;
    }
  }
  // ---- stage x1 [3][34][36] origin (oy0-1, ox0-1) into s_ov ----
  for (int q = tid; q < NC1; q += 256) {
    const int colq = q % (X1S / 4);
    const int rp   = q / (X1S / 4);
    const int r    = rp % X1R;
    const int c    = rp / X1R;
    const int gy   = oy0 - 1 + r;
    const int gx0  = ox0 - 1 + colq * 4;
    const float* src = x1b + (size_t)(c * HH + gy) * WW + gx0;
    if ((unsigned)gy < HH && (unsigned)gx0 <= (WW - 4)) {
      __builtin_amdgcn_global_load_lds((gas_ptr)src,
          (las_ptr)(s_ov + ((q & ~63) << 2)), 16, 0, 0);
    } else {
      const bool rowok = (unsigned)gy < HH;
      float4 v;
      v.x = (rowok && (unsigned)(gx0 + 0) < WW) ? src[0] : 0.f;
      v.y = (rowok && (unsigned)(gx0 + 1) < WW) ? src[1] : 0.f;
      v.z = (rowok && (unsigned)(gx0 + 2) < WW) ? src[2] : 0.f;
      v.w = (rowok && (unsigned)(gx0 + 3) < WW) ? src[3] : 0.f;
      *reinterpret_cast<float4*>(&s_ov[q * 4]) = v;
    }
  }
  __syncthreads();   // staging complete

  // ---- phase B: f2 (regs) from s_x2, f1 (regs) from s_ov-as-x1 ----
  auto f2unit = [&](int r, int col0, float acc[3][4]) {
    #pragma unroll
    for (int co = 0; co < 3; ++co)
      #pragma unroll
      for (int j = 0; j < 4; ++j) acc[co][j] = 0.f;
    #pragma unroll
    for (int ci = 0; ci < 3; ++ci) {
      float win[3][6];
      #pragma unroll
      for (int ky = 0; ky < 3; ++ky) {
        const float* base = &s_x2[(ci * X2R + r + ky) * X2S + col0];
        const float4 a  = *reinterpret_cast<const float4*>(base);
        const float2 b2 = *reinterpret_cast<const float2*>(base + 4);
        win[ky][0] = a.x; win[ky][1] = a.y; win[ky][2] = a.z; win[ky][3] = a.w;
        win[ky][4] = b2.x; win[ky][5] = b2.y;
      }
      #pragma unroll
      for (int co = 0; co < 3; ++co)
        #pragma unroll
        for (int ky = 0; ky < 3; ++ky)
          #pragma unroll
          for (int kx = 0; kx < 3; ++kx) {
            const float w = cw[((co * 3 + ci) * 3 + ky) * 3 + kx]; // uniform -> SGPR
            #pragma unroll
            for (int j = 0; j < 4; ++j)
              acc[co][j] += w * win[ky][j + kx];
          }
    }
    // correlation zero-pads f2: zero outside the image
    const int gy = oy0 - 2 + r;
    #pragma unroll
    for (int j = 0; j < 4; ++j) {
      const int gx = ox0 - 2 + col0 + j;
      if (!((unsigned)gy < HH && (unsigned)gx < WW)) {
        acc[0][j] = 0.f; acc[1][j] = 0.f; acc[2][j] = 0.f;
      }
    }
  };

  // main 256 units: conflict-free regular mapping
  const int r0   = tid >> 3;          // 0..31
  const int c0   = (tid & 7) << 2;    // 0..28
  float acc0[3][4];
  f2unit(r0, c0, acc0);
  // cleanup 68 units: rows 32-35 x 9 segs (36) + seg 8 of rows 0-31 (32)
  float acc1[3][4];
  int r1 = 0, c1 = 0;
  if (tid < 68) {
    if (tid < 36) { r1 = 32 + tid / 9; c1 = (tid % 9) * 4; }
    else          { r1 = tid - 36;     c1 = 32; }
    f2unit(r1, c1, acc1);
  }

  // f1 for run of 4: row py, cols px0..px0+3
  const int py  = tid >> 3;
  const int px0 = (tid & 7) << 2;
  float f1r[3][4] = {};
  #pragma unroll
  for (int ci = 0; ci < 3; ++ci) {
    float win[3][6];
    #pragma unroll
    for (int ky = 0; ky < 3; ++ky) {
      const float* base = &s_ov[(ci * X1R + py + ky) * X1S + px0];
      const float4 a  = *reinterpret_cast<const float4*>(base);
      const float2 b2 = *reinterpret_cast<const float2*>(base + 4);
      win[ky][0] = a.x; win[ky][1] = a.y; win[ky][2] = a.z; win[ky][3] = a.w;
      win[ky][4] = b2.x; win[ky][5] = b2.y;
    }
    #pragma unroll
    for (int co = 0; co < 3; ++co)
      #pragma unroll
      for (int ky = 0; ky < 3; ++ky)
        #pragma unroll
        for (int kx = 0; kx < 3; ++kx) {
          const float w = cw[((co * 3 + ci) * 3 + ky) * 3 + kx];
          #pragma unroll
          for (int j = 0; j < 4; ++j)
            f1r[co][j] += w * win[ky][j + kx];
        }
  }
  #pragma unroll
  for (int co = 0; co < 3; ++co)
    #pragma unroll
    for (int j = 0; j < 4; ++j)
      f1r[co][j] *= (1.f / 3.f);     // fold mean divisor
  __syncthreads();   // all reads of s_ov-as-x1 / s_x2 done

  // ---- phase C: write f2 regs into s_ov overlay ----
  #pragma unroll
  for (int co = 0; co < 3; ++co)
    *reinterpret_cast<float4*>(&s_ov[(co * F2R + r0) * F2S + c0]) =
        make_float4(acc0[co][0], acc0[co][1], acc0[co][2], acc0[co][3]);
  if (tid < 68) {
    #pragma unroll
    for (int co = 0; co < 3; ++co)
      *reinterpret_cast<float4*>(&s_ov[(co * F2R + r1) * F2S + c1]) =
          make_float4(acc1[co][0], acc1[co][1], acc1[co][2], acc1[co][3]);
  }
  __syncthreads();   // f2 tile ready

  // ---- correlation + nontemporal dwordx4 stores ----
  float* outp = out + ((size_t)bi * 9 * HH + (oy0 + py)) * WW + ox0 + px0;
  #pragma unroll
  for (int dyi = 0; dyi < 3; ++dyi) {
    float rv[3][8];
    #pragma unroll
    for (int c = 0; c < 3; ++c) {
      const float* base = &s_ov[(c * F2R + py + dyi * 2) * F2S + px0];
      const float4 a = *reinterpret_cast<const float4*>(base);
      const float4 b = *reinterpret_cast<const float4*>(base + 4);
      rv[c][0] = a.x; rv[c][1] = a.y; rv[c][2] = a.z; rv[c][3] = a.w;
      rv[c][4] = b.x; rv[c][5] = b.y; rv[c][6] = b.z; rv[c][7] = b.w;
    }
    #pragma unroll
    for (int dxi = 0; dxi < 3; ++dxi) {
      const int s = dxi * 2;
      f32x4 o;
      o.x = f1r[0][0]*rv[0][s+0] + f1r[1][0]*rv[1][s+0] + f1r[2][0]*rv[2][s+0];
      o.y = f1r[0][1]*rv[0][s+1] + f1r[1][1]*rv[1][s+1] + f1r[2][1]*rv[2][s+1];
      o.z = f1r[0][2]*rv[0][s+2] + f1r[1][2]*rv[1][s+2] + f1r[2][2]*rv[2][s+2];
      o.w = f1r[0][3]*rv[0][s+3] + f1r[1][3]*rv[1][s+3] + f1r[2][3]*rv[2][s+3];
      __builtin_nontemporal_store(o,
          reinterpret_cast<f32x4*>(outp + (size_t)(dyi * 3 + dxi) * HH * WW));
    }
  }
}

extern "C" void kernel_launch(void* const* d_in, const int* in_sizes, int n_in,
                              void* d_out, int out_size, void* d_ws, size_t ws_size,
                              hipStream_t stream) {
  const float* x1 = (const float*)d_in[0];
  const float* x2 = (const float*)d_in[1];
  const float* cw = (const float*)d_in[2];
  float* out = (float*)d_out;

  flownetc_fused_kernel<<<dim3(4096), 256, 0, stream>>>(x1, x2, cw, out);
}

// Round 17
// 57.397 us; speedup vs baseline: 1.5149x; 1.0116x over previous
//
#include <hip/hip_runtime.h>

// FlowNetC fused: f1=conv3x3(x1,w), f2=conv3x3(x2,w),
// out[b,k,h,w] = mean_c f1[b,c,h,w]*f2[b,c,h+dy,w+dx], dy,dx in {-2,0,2}
// B=16,C=3,H=W=512,K=9. f32.
//
// R17 = R10 with ONE change: swizzle makes consecutive blocks Y-adjacent
// (vertical neighbors share 5-6 full halo ROWS -> contiguous L1/L2 lines;
// horizontal neighbors only share sparse halo columns). Everything else
// identical to R10 (58.1us): 32x32 tile / 256 thr, LDS overlay, 3 barriers,
// conflict-free f2 mapping, scalar-pipe weights, width-16 global_load_lds,
// 1/3 folded into f1, NT dwordx4 stores. LDS 35.5KB -> 4 blocks/CU.

#define HH 512
#define WW 512
#define TS 32
#define X2R 38
#define X2S 40              // x2 stride, rows 160B-aligned
#define X1R 34
#define X1S 36              // x1 stride, rows 144B-aligned
#define F2R 36
#define F2S 40
#define N2 (3*X2R*X2S)      // 4560 words
#define NF (3*F2R*F2S)      // 4320 words (overlay region size)
#define NC2 (3*X2R*(X2S/4)) // 1140 16B chunks
#define NC1 (3*X1R*(X1S/4)) // 918

typedef const __attribute__((address_space(1))) void* gas_ptr;
typedef __attribute__((address_space(3))) void* las_ptr;
typedef float f32x4 __attribute__((ext_vector_type(4)));

__global__ __launch_bounds__(256)
void flownetc_fused_kernel(const float* __restrict__ x1,
                           const float* __restrict__ x2,
                           const float* __restrict__ cw,
                           float* __restrict__ out) {
  __shared__ __align__(16) float s_x2[N2];
  __shared__ __align__(16) float s_ov[NF];   // x1 staging (first NC1*4) then f2

  const int tid = threadIdx.x;
  // XCD-contiguous swizzle, Y fastest: vertical neighbors consecutive
  const int bid = blockIdx.x;
  const int f   = (bid & 7) * 512 + (bid >> 3);
  const int oy0 = (f & 15) * TS;           // y fastest-varying
  const int ox0 = ((f >> 4) & 15) * TS;
  const int bi  = f >> 8;

  const float* x2b = x2 + (size_t)bi * 3 * HH * WW;
  const float* x1b = x1 + (size_t)bi * 3 * HH * WW;

  // ---- stage x2 [3][38][40] origin (oy0-3, ox0-3), 16B chunks ----
  for (int q = tid; q < NC2; q += 256) {
    const int colq = q % (X2S / 4);
    const int rp   = q / (X2S / 4);
    const int r    = rp % X2R;
    const int c    = rp / X2R;
    const int gy   = oy0 - 3 + r;
    const int gx0  = ox0 - 3 + colq * 4;
    const float* src = x2b + (size_t)(c * HH + gy) * WW + gx0;
    if ((unsigned)gy < HH && (unsigned)gx0 <= (WW - 4)) {
      __builtin_amdgcn_global_load_lds((gas_ptr)src,
          (las_ptr)(s_x2 + ((q & ~63) << 2)), 16, 0, 0);
    } else {
      const bool rowok = (unsigned)gy < HH;
      float4 v;
      v.x = (rowok && (unsigned)(gx0 + 0) < WW) ? src[0] : 0.f;
      v.y = (rowok && (unsigned)(gx0 + 1) < WW) ? src[1] : 0.f;
      v.z = (rowok && (unsigned)(gx0 + 2) < WW) ? src[2] : 0.f;
      v.w = (rowok && (unsigned)(gx0 + 3) < WW) ? src[3] : 0.f;
      *reinterpret_cast<float4*>(&s_x2[q * 4]) = v;
    }
  }
  // ---- stage x1 [3][34][36] origin (oy0-1, ox0-1) into s_ov ----
  for (int q = tid; q < NC1; q += 256) {
    const int colq = q % (X1S / 4);
    const int rp   = q / (X1S / 4);
    const int r    = rp % X1R;
    const int c    = rp / X1R;
    const int gy   = oy0 - 1 + r;
    const int gx0  = ox0 - 1 + colq * 4;
    const float* src = x1b + (size_t)(c * HH + gy) * WW + gx0;
    if ((unsigned)gy < HH && (unsigned)gx0 <= (WW - 4)) {
      __builtin_amdgcn_global_load_lds((gas_ptr)src,
          (las_ptr)(s_ov + ((q & ~63) << 2)), 16, 0, 0);
    } else {
      const bool rowok = (unsigned)gy < HH;
      float4 v;
      v.x = (rowok && (unsigned)(gx0 + 0) < WW) ? src[0] : 0.f;
      v.y = (rowok && (unsigned)(gx0 + 1) < WW) ? src[1] : 0.f;
      v.z = (rowok && (unsigned)(gx0 + 2) < WW) ? src[2] : 0.f;
      v.w = (rowok && (unsigned)(gx0 + 3) < WW) ? src[3] : 0.f;
      *reinterpret_cast<float4*>(&s_ov[q * 4]) = v;
    }
  }
  __syncthreads();   // staging complete

  // ---- phase B: f2 (regs) from s_x2, f1 (regs) from s_ov-as-x1 ----
  auto f2unit = [&](int r, int col0, float acc[3][4]) {
    #pragma unroll
    for (int co = 0; co < 3; ++co)
      #pragma unroll
      for (int j = 0; j < 4; ++j) acc[co][j] = 0.f;
    #pragma unroll
    for (int ci = 0; ci < 3; ++ci) {
      float win[3][6];
      #pragma unroll
      for (int ky = 0; ky < 3; ++ky) {
        const float* base = &s_x2[(ci * X2R + r + ky) * X2S + col0];
        const float4 a  = *reinterpret_cast<const float4*>(base);
        const float2 b2 = *reinterpret_cast<const float2*>(base + 4);
        win[ky][0] = a.x; win[ky][1] = a.y; win[ky][2] = a.z; win[ky][3] = a.w;
        win[ky][4] = b2.x; win[ky][5] = b2.y;
      }
      #pragma unroll
      for (int co = 0; co < 3; ++co)
        #pragma unroll
        for (int ky = 0; ky < 3; ++ky)
          #pragma unroll
          for (int kx = 0; kx < 3; ++kx) {
            const float w = cw[((co * 3 + ci) * 3 + ky) * 3 + kx]; // uniform -> SGPR
            #pragma unroll
            for (int j = 0; j < 4; ++j)
              acc[co][j] += w * win[ky][j + kx];
          }
    }
    // correlation zero-pads f2: zero outside the image
    const int gy = oy0 - 2 + r;
    #pragma unroll
    for (int j = 0; j < 4; ++j) {
      const int gx = ox0 - 2 + col0 + j;
      if (!((unsigned)gy < HH && (unsigned)gx < WW)) {
        acc[0][j] = 0.f; acc[1][j] = 0.f; acc[2][j] = 0.f;
      }
    }
  };

  // main 256 units: conflict-free regular mapping
  const int r0   = tid >> 3;          // 0..31
  const int c0   = (tid & 7) << 2;    // 0..28
  float acc0[3][4];
  f2unit(r0, c0, acc0);
  // cleanup 68 units: rows 32-35 x 9 segs (36) + seg 8 of rows 0-31 (32)
  float acc1[3][4];
  int r1 = 0, c1 = 0;
  if (tid < 68) {
    if (tid < 36) { r1 = 32 + tid / 9; c1 = (tid % 9) * 4; }
    else          { r1 = tid - 36;     c1 = 32; }
    f2unit(r1, c1, acc1);
  }

  // f1 for run of 4: row py, cols px0..px0+3
  const int py  = tid >> 3;
  const int px0 = (tid & 7) << 2;
  float f1r[3][4] = {};
  #pragma unroll
  for (int ci = 0; ci < 3; ++ci) {
    float win[3][6];
    #pragma unroll
    for (int ky = 0; ky < 3; ++ky) {
      const float* base = &s_ov[(ci * X1R + py + ky) * X1S + px0];
      const float4 a  = *reinterpret_cast<const float4*>(base);
      const float2 b2 = *reinterpret_cast<const float2*>(base + 4);
      win[ky][0] = a.x; win[ky][1] = a.y; win[ky][2] = a.z; win[ky][3] = a.w;
      win[ky][4] = b2.x; win[ky][5] = b2.y;
    }
    #pragma unroll
    for (int co = 0; co < 3; ++co)
      #pragma unroll
      for (int ky = 0; ky < 3; ++ky)
        #pragma unroll
        for (int kx = 0; kx < 3; ++kx) {
          const float w = cw[((co * 3 + ci) * 3 + ky) * 3 + kx];
          #pragma unroll
          for (int j = 0; j < 4; ++j)
            f1r[co][j] += w * win[ky][j + kx];
        }
  }
  #pragma unroll
  for (int co = 0; co < 3; ++co)
    #pragma unroll
    for (int j = 0; j < 4; ++j)
      f1r[co][j] *= (1.f / 3.f);     // fold mean divisor
  __syncthreads();   // all reads of s_ov-as-x1 / s_x2 done

  // ---- phase C: write f2 regs into s_ov overlay ----
  #pragma unroll
  for (int co = 0; co < 3; ++co)
    *reinterpret_cast<float4*>(&s_ov[(co * F2R + r0) * F2S + c0]) =
        make_float4(acc0[co][0], acc0[co][1], acc0[co][2], acc0[co][3]);
  if (tid < 68) {
    #pragma unroll
    for (int co = 0; co < 3; ++co)
      *reinterpret_cast<float4*>(&s_ov[(co * F2R + r1) * F2S + c1]) =
          make_float4(acc1[co][0], acc1[co][1], acc1[co][2], acc1[co][3]);
  }
  __syncthreads();   // f2 tile ready

  // ---- correlation + nontemporal dwordx4 stores ----
  float* outp = out + ((size_t)bi * 9 * HH + (oy0 + py)) * WW + ox0 + px0;
  #pragma unroll
  for (int dyi = 0; dyi < 3; ++dyi) {
    float rv[3][8];
    #pragma unroll
    for (int c = 0; c < 3; ++c) {
      const float* base = &s_ov[(c * F2R + py + dyi * 2) * F2S + px0];
      const float4 a = *reinterpret_cast<const float4*>(base);
      const float4 b = *reinterpret_cast<const float4*>(base + 4);
      rv[c][0] = a.x; rv[c][1] = a.y; rv[c][2] = a.z; rv[c][3] = a.w;
      rv[c][4] = b.x; rv[c][5] = b.y; rv[c][6] = b.z; rv[c][7] = b.w;
    }
    #pragma unroll
    for (int dxi = 0; dxi < 3; ++dxi) {
      const int s = dxi * 2;
      f32x4 o;
      o.x = f1r[0][0]*rv[0][s+0] + f1r[1][0]*rv[1][s+0] + f1r[2][0]*rv[2][s+0];
      o.y = f1r[0][1]*rv[0][s+1] + f1r[1][1]*rv[1][s+1] + f1r[2][1]*rv[2][s+1];
      o.z = f1r[0][2]*rv[0][s+2] + f1r[1][2]*rv[1][s+2] + f1r[2][2]*rv[2][s+2];
      o.w = f1r[0][3]*rv[0][s+3] + f1r[1][3]*rv[1][s+3] + f1r[2][3]*rv[2][s+3];
      __builtin_nontemporal_store(o,
          reinterpret_cast<f32x4*>(outp + (size_t)(dyi * 3 + dxi) * HH * WW));
    }
  }
}

extern "C" void kernel_launch(void* const* d_in, const int* in_sizes, int n_in,
                              void* d_out, int out_size, void* d_ws, size_t ws_size,
                              hipStream_t stream) {
  const float* x1 = (const float*)d_in[0];
  const float* x2 = (const float*)d_in[1];
  const float* cw = (const float*)d_in[2];
  float* out = (float*)d_out;

  flownetc_fused_kernel<<<dim3(4096), 256, 0, stream>>>(x1, x2, cw, out);
}

// Round 18
// 57.199 us; speedup vs baseline: 1.5201x; 1.0035x over previous
//
#include <hip/hip_runtime.h>

// FlowNetC fused: f1=conv3x3(x1,w), f2=conv3x3(x2,w),
// out[b,k,h,w] = mean_c f1[b,c,h,w]*f2[b,c,h+dy,w+dx], dy,dx in {-2,0,2}
// B=16,C=3,H=W=512,K=9. f32.
//
// R18: SMALLER blocks for phase decorrelation. 16x32 tile / 128 threads
// (2 waves), LDS 19.2KB -> 8 blocks/CU = 16 waves in 8 independent
// barrier groups (vs R17's 4). Same per-thread pattern as R17 otherwise:
// LDS overlay (x1 staging then f2 tile in s_ov), 3 barriers, conflict-free
// f2 mapping, scalar-pipe weights, width-16 global_load_lds, 1/3 folded
// into f1, NT dwordx4 stores, y-fastest XCD-contiguous swizzle.

#define HH 512
#define WW 512
#define TSX 32
#define TSY 16
#define X2R 22              // TSY+6
#define X2S 40              // stride words, 160B rows
#define X1R 18              // TSY+2
#define X1S 36              // 144B rows
#define F2R 20              // TSY+4
#define F2S 36              // 144B rows (overlay region)
#define N2 (3*X2R*X2S)      // 2640 words
#define NF (3*F2R*F2S)      // 2160 words (>= x1's 1944)
#define NC2 (3*X2R*(X2S/4)) // 660 chunks
#define NC1 (3*X1R*(X1S/4)) // 486 chunks

typedef const __attribute__((address_space(1))) void* gas_ptr;
typedef __attribute__((address_space(3))) void* las_ptr;
typedef float f32x4 __attribute__((ext_vector_type(4)));

__global__ __launch_bounds__(128)
void flownetc_fused_kernel(const float* __restrict__ x1,
                           const float* __restrict__ x2,
                           const float* __restrict__ cw,
                           float* __restrict__ out) {
  __shared__ __align__(16) float s_x2[N2];
  __shared__ __align__(16) float s_ov[NF];   // x1 staging, then f2 tile

  const int tid = threadIdx.x;
  // XCD-contiguous swizzle, y fastest: 8192 blocks / 8 XCDs = 1024 each
  const int bid = blockIdx.x;
  const int f   = (bid & 7) * 1024 + (bid >> 3);
  const int oy0 = (f & 31) * TSY;          // 32 y-tiles, fastest
  const int ox0 = ((f >> 5) & 15) * TSX;   // 16 x-tiles
  const int bi  = f >> 9;                  // 16 batches

  const float* x2b = x2 + (size_t)bi * 3 * HH * WW;
  const float* x1b = x1 + (size_t)bi * 3 * HH * WW;

  // ---- stage x2 [3][22][40] origin (oy0-3, ox0-3), 16B chunks ----
  for (int q = tid; q < NC2; q += 128) {
    const int colq = q % (X2S / 4);
    const int rp   = q / (X2S / 4);
    const int r    = rp % X2R;
    const int c    = rp / X2R;
    const int gy   = oy0 - 3 + r;
    const int gx0  = ox0 - 3 + colq * 4;
    const float* src = x2b + (size_t)(c * HH + gy) * WW + gx0;
    if ((unsigned)gy < HH && (unsigned)gx0 <= (WW - 4)) {
      __builtin_amdgcn_global_load_lds((gas_ptr)src,
          (las_ptr)(s_x2 + ((q & ~63) << 2)), 16, 0, 0);
    } else {
      const bool rowok = (unsigned)gy < HH;
      float4 v;
      v.x = (rowok && (unsigned)(gx0 + 0) < WW) ? src[0] : 0.f;
      v.y = (rowok && (unsigned)(gx0 + 1) < WW) ? src[1] : 0.f;
      v.z = (rowok && (unsigned)(gx0 + 2) < WW) ? src[2] : 0.f;
      v.w = (rowok && (unsigned)(gx0 + 3) < WW) ? src[3] : 0.f;
      *reinterpret_cast<float4*>(&s_x2[q * 4]) = v;
    }
  }
  // ---- stage x1 [3][18][36] origin (oy0-1, ox0-1) into s_ov ----
  for (int q = tid; q < NC1; q += 128) {
    const int colq = q % (X1S / 4);
    const int rp   = q / (X1S / 4);
    const int r    = rp % X1R;
    const int c    = rp / X1R;
    const int gy   = oy0 - 1 + r;
    const int gx0  = ox0 - 1 + colq * 4;
    const float* src = x1b + (size_t)(c * HH + gy) * WW + gx0;
    if ((unsigned)gy < HH && (unsigned)gx0 <= (WW - 4)) {
      __builtin_amdgcn_global_load_lds((gas_ptr)src,
          (las_ptr)(s_ov + ((q & ~63) << 2)), 16, 0, 0);
    } else {
      const bool rowok = (unsigned)gy < HH;
      float4 v;
      v.x = (rowok && (unsigned)(gx0 + 0) < WW) ? src[0] : 0.f;
      v.y = (rowok && (unsigned)(gx0 + 1) < WW) ? src[1] : 0.f;
      v.z = (rowok && (unsigned)(gx0 + 2) < WW) ? src[2] : 0.f;
      v.w = (rowok && (unsigned)(gx0 + 3) < WW) ? src[3] : 0.f;
      *reinterpret_cast<float4*>(&s_ov[q * 4]) = v;
    }
  }
  __syncthreads();   // staging complete

  // ---- phase B: f2 (regs) from s_x2, f1 (regs) from s_ov-as-x1 ----
  auto f2unit = [&](int r, int col0, float acc[3][4]) {
    #pragma unroll
    for (int co = 0; co < 3; ++co)
      #pragma unroll
      for (int j = 0; j < 4; ++j) acc[co][j] = 0.f;
    #pragma unroll
    for (int ci = 0; ci < 3; ++ci) {
      float win[3][6];
      #pragma unroll
      for (int ky = 0; ky < 3; ++ky) {
        const float* base = &s_x2[(ci * X2R + r + ky) * X2S + col0];
        const float4 a  = *reinterpret_cast<const float4*>(base);
        const float2 b2 = *reinterpret_cast<const float2*>(base + 4);
        win[ky][0] = a.x; win[ky][1] = a.y; win[ky][2] = a.z; win[ky][3] = a.w;
        win[ky][4] = b2.x; win[ky][5] = b2.y;
      }
      #pragma unroll
      for (int co = 0; co < 3; ++co)
        #pragma unroll
        for (int ky = 0; ky < 3; ++ky)
          #pragma unroll
          for (int kx = 0; kx < 3; ++kx) {
            const float w = cw[((co * 3 + ci) * 3 + ky) * 3 + kx]; // SGPR
            #pragma unroll
            for (int j = 0; j < 4; ++j)
              acc[co][j] += w * win[ky][j + kx];
          }
    }
    // correlation zero-pads f2: zero outside the image
    const int gy = oy0 - 2 + r;
    #pragma unroll
    for (int j = 0; j < 4; ++j) {
      const int gx = ox0 - 2 + col0 + j;
      if (!((unsigned)gy < HH && (unsigned)gx < WW)) {
        acc[0][j] = 0.f; acc[1][j] = 0.f; acc[2][j] = 0.f;
      }
    }
  };

  // main 128 units: r=tid>>3 (0..15), col=(tid&7)*4 (0..28)
  const int r0   = tid >> 3;
  const int c0   = (tid & 7) << 2;
  float acc0[3][4];
  f2unit(r0, c0, acc0);
  // cleanup 52 units: rows 16-19 x 9 segs (36) + seg 8 of rows 0-15 (16)
  float acc1[3][4];
  int r1 = 0, c1 = 0;
  if (tid < 52) {
    if (tid < 36) { r1 = 16 + tid / 9; c1 = (tid % 9) * 4; }
    else          { r1 = tid - 36;     c1 = 32; }
    f2unit(r1, c1, acc1);
  }

  // f1 for run of 4: row py (0..15), cols px0..px0+3
  const int py  = tid >> 3;
  const int px0 = (tid & 7) << 2;
  float f1r[3][4] = {};
  #pragma unroll
  for (int ci = 0; ci < 3; ++ci) {
    float win[3][6];
    #pragma unroll
    for (int ky = 0; ky < 3; ++ky) {
      const float* base = &s_ov[(ci * X1R + py + ky) * X1S + px0];
      const float4 a  = *reinterpret_cast<const float4*>(base);
      const float2 b2 = *reinterpret_cast<const float2*>(base + 4);
      win[ky][0] = a.x; win[ky][1] = a.y; win[ky][2] = a.z; win[ky][3] = a.w;
      win[ky][4] = b2.x; win[ky][5] = b2.y;
    }
    #pragma unroll
    for (int co = 0; co < 3; ++co)
      #pragma unroll
      for (int ky = 0; ky < 3; ++ky)
        #pragma unroll
        for (int kx = 0; kx < 3; ++kx) {
          const float w = cw[((co * 3 + ci) * 3 + ky) * 3 + kx];
          #pragma unroll
          for (int j = 0; j < 4; ++j)
            f1r[co][j] += w * win[ky][j + kx];
        }
  }
  #pragma unroll
  for (int co = 0; co < 3; ++co)
    #pragma unroll
    for (int j = 0; j < 4; ++j)
      f1r[co][j] *= (1.f / 3.f);     // fold mean divisor
  __syncthreads();   // all reads of s_ov-as-x1 / s_x2 done

  // ---- phase C: write f2 regs into s_ov overlay [3][20][36] ----
  #pragma unroll
  for (int co = 0; co < 3; ++co)
    *reinterpret_cast<float4*>(&s_ov[(co * F2R + r0) * F2S + c0]) =
        make_float4(acc0[co][0], acc0[co][1], acc0[co][2], acc0[co][3]);
  if (tid < 52) {
    #pragma unroll
    for (int co = 0; co < 3; ++co)
      *reinterpret_cast<float4*>(&s_ov[(co * F2R + r1) * F2S + c1]) =
          make_float4(acc1[co][0], acc1[co][1], acc1[co][2], acc1[co][3]);
  }
  __syncthreads();   // f2 tile ready

  // ---- correlation + nontemporal dwordx4 stores ----
  float* outp = out + ((size_t)bi * 9 * HH + (oy0 + py)) * WW + ox0 + px0;
  #pragma unroll
  for (int dyi = 0; dyi < 3; ++dyi) {
    float rv[3][8];
    #pragma unroll
    for (int c = 0; c < 3; ++c) {
      const float* base = &s_ov[(c * F2R + py + dyi * 2) * F2S + px0];
      const float4 a = *reinterpret_cast<const float4*>(base);
      const float4 b = *reinterpret_cast<const float4*>(base + 4);
      rv[c][0] = a.x; rv[c][1] = a.y; rv[c][2] = a.z; rv[c][3] = a.w;
      rv[c][4] = b.x; rv[c][5] = b.y; rv[c][6] = b.z; rv[c][7] = b.w;
    }
    #pragma unroll
    for (int dxi = 0; dxi < 3; ++dxi) {
      const int s = dxi * 2;
      f32x4 o;
      o.x = f1r[0][0]*rv[0][s+0] + f1r[1][0]*rv[1][s+0] + f1r[2][0]*rv[2][s+0];
      o.y = f1r[0][1]*rv[0][s+1] + f1r[1][1]*rv[1][s+1] + f1r[2][1]*rv[2][s+1];
      o.z = f1r[0][2]*rv[0][s+2] + f1r[1][2]*rv[1][s+2] + f1r[2][2]*rv[2][s+2];
      o.w = f1r[0][3]*rv[0][s+3] + f1r[1][3]*rv[1][s+3] + f1r[2][3]*rv[2][s+3];
      __builtin_nontemporal_store(o,
          reinterpret_cast<f32x4*>(outp + (size_t)(dyi * 3 + dxi) * HH * WW));
    }
  }
}

extern "C" void kernel_launch(void* const* d_in, const int* in_sizes, int n_in,
                              void* d_out, int out_size, void* d_ws, size_t ws_size,
                              hipStream_t stream) {
  const float* x1 = (const float*)d_in[0];
  const float* x2 = (const float*)d_in[1];
  const float* cw = (const float*)d_in[2];
  float* out = (float*)d_out;

  // 16 x-tiles * 32 y-tiles * 16 batches = 8192 blocks of 128 threads
  flownetc_fused_kernel<<<dim3(8192), 128, 0, stream>>>(x1, x2, cw, out);
}